// Round 3
// baseline (499.828 us; speedup 1.0000x reference)
//
#include <hip/hip_runtime.h>

// ConvLSTM2D (B=16,T=5,H=W=256,Cin=3,F=8) + BN + LeakyReLU + Dense(8->2)
// Round-12: identical to r11 (never executed — broker timeout). Persistent
// single kernel, sync via hand-rolled grid barrier (agent-scope atomics in
// workspace) + normal launch. Co-residency of all 512 blocks guaranteed by
// __launch_bounds__(256,2) (VGPR<=256 -> 8 waves/CU) + 47.5KB LDS (2/CU).
// c state lives in LDS whole run (no c HBM traffic), B-frags loaded once,
// 4 barriers replace 4 launch boundaries.

#define BB  16
#define TT  5
#define HH  256
#define WW  256
#define CIN 3
#define FF  8
#define GG  32

#define TW  32   // tile width (pixels)
#define THT 16   // tile height
#define LW  34   // TW+2 halo
#define LH  18   // THT+2 halo
#define NG  8    // 16x16-px groups per wave

#define NBLK  512   // persistent blocks (2 per CU)
#define SLOTS 4     // tiles per block = 2048/NBLK

#define LOG2E 1.44269504088896340736f

typedef _Float16 half8  __attribute__((ext_vector_type(8)));
typedef _Float16 half4  __attribute__((ext_vector_type(4)));
typedef _Float16 half2t __attribute__((ext_vector_type(2)));
typedef float    floatx4 __attribute__((ext_vector_type(4)));

__device__ __forceinline__ float frcp(float x) { return __builtin_amdgcn_rcpf(x); }
// z pre-scaled by -log2e:  sigmoid(z0) = 1/(1+2^z)
__device__ __forceinline__ float sig2(float z)  { return frcp(1.0f + __builtin_amdgcn_exp2f(z)); }
// z pre-scaled by +2log2e: tanh(z0) = 1 - 2/(1+2^z)
__device__ __forceinline__ float tanh2(float z) { return 1.0f - 2.0f * frcp(1.0f + __builtin_amdgcn_exp2f(z)); }

#define MFMA(A, B, C) __builtin_amdgcn_mfma_f32_16x16x32_f16((A), (B), (C), 0, 0, 0)

// ---------------------------------------------------------------------------
// Sense-reversing grid barrier. bar[0]=arrival count, bar[1]=generation.
// Agent-scope release on arrival makes this block's prior global stores
// visible device-wide (L2 writeback); agent-scope acquire on the spin / the
// generation flip makes them visible to us (L2 invalidate). __syncthreads
// drains each wave's vmcnt before thread 0 arrives.
// ---------------------------------------------------------------------------
__device__ __forceinline__ void grid_barrier(unsigned* bar) {
    __syncthreads();
    if (threadIdx.x == 0) {
        const unsigned gen =
            __hip_atomic_load(&bar[1], __ATOMIC_RELAXED, __HIP_MEMORY_SCOPE_AGENT);
        const unsigned old =
            __hip_atomic_fetch_add(&bar[0], 1u, __ATOMIC_ACQ_REL, __HIP_MEMORY_SCOPE_AGENT);
        if (old == NBLK - 1u) {
            __hip_atomic_store(&bar[0], 0u, __ATOMIC_RELAXED, __HIP_MEMORY_SCOPE_AGENT);
            __hip_atomic_store(&bar[1], gen + 1u, __ATOMIC_RELEASE, __HIP_MEMORY_SCOPE_AGENT);
        } else {
            while (__hip_atomic_load(&bar[1], __ATOMIC_ACQUIRE,
                                     __HIP_MEMORY_SCOPE_AGENT) == gen) {
                __builtin_amdgcn_s_sleep(2);
            }
        }
    }
    __syncthreads();
}

// ---------------------------------------------------------------------------
// Setup: 16 B-fragments, activation scale folded per column:
// cols 0..15 (i,f) and 24..31 (o): *(-log2e); cols 16..23 (g): *(+2log2e).
// frag 0..9 = hi (chunks 0..4 x 2 col-halves); frag 10..15 = lo for h-conv
// chunks 2..4 (x-conv lo dropped). MFMA B layout: n = lane&15, k = quad*8+j.
// K-chunks: 0: x taps0-7 (k=tap*4+ci, ci padded to 4)
//           1: x tap8   (k=ci, only k<3 nonzero)
//           2..4: h taps [4c..4c+3] (k=(tap-4c)*8+ci), taps>8 zero
// Also zero-inits the grid-barrier words (self-resetting across replays).
// ---------------------------------------------------------------------------
__global__ void build_frags(const float* __restrict__ wk,
                            const float* __restrict__ wr,
                            _Float16* __restrict__ blob,
                            unsigned* __restrict__ bar) {
    if (threadIdx.x == 0) { bar[0] = 0u; bar[1] = 0u; }
    const int lane = threadIdx.x & 63;
    const int quad = lane >> 4, nlo = lane & 15;
    for (int chunk = 0; chunk < 5; ++chunk) {
        for (int nh = 0; nh < 2; ++nh) {
            const int n = nh * 16 + nlo;
            const float scale = (n >= 16 && n < 24) ? (2.0f * LOG2E) : (-LOG2E);
            const int frag = chunk * 2 + nh;
            _Float16* dhi = blob + ((size_t)frag * 64 + lane) * 8;
            _Float16* dlo = (chunk >= 2)
                ? blob + ((size_t)(10 + (chunk - 2) * 2 + nh) * 64 + lane) * 8
                : nullptr;
            for (int j = 0; j < 8; ++j) {
                const int k = quad * 8 + j;
                float w = 0.0f;
                if (chunk == 0) {
                    int tap = k >> 2, ci = k & 3;
                    if (ci < 3) w = wk[(tap * 3 + ci) * GG + n];
                } else if (chunk == 1) {
                    if (quad == 0 && j < 3) w = wk[(8 * 3 + j) * GG + n];
                } else {
                    int c = chunk - 2;
                    int tap = c * 4 + quad, ci = j;
                    if (tap < 9) w = wr[(tap * FF + ci) * GG + n];
                }
                w *= scale;
                _Float16 wh = (_Float16)w;
                dhi[j] = wh;
                if (dlo) dlo[j] = (_Float16)(w - (float)wh);
            }
        }
    }
}

// ---------------------------------------------------------------------------
// Persistent kernel: all TT timesteps, grid barrier between them.
// Block = 256 thr (4 waves); block owns SLOTS tiles of 32x16 px.
// c state: LDS resident for whole run. h: global fp16 ping-pong (halo).
// ---------------------------------------------------------------------------
__global__ __launch_bounds__(256, 2) void lstm_all(
    const float* __restrict__ xg,       // [B,T,H,W,3] fp32
    const _Float16* __restrict__ blob,  // scaled B-fragments (hi 0..9, lo 10..15)
    const float* __restrict__ bias,     // [32] (unscaled; scaled here)
    _Float16* __restrict__ h0,          // ping-pong h buffers
    _Float16* __restrict__ h1,
    unsigned* __restrict__ bar,         // grid barrier state
    const float* __restrict__ gamma, const float* __restrict__ beta,
    const float* __restrict__ mean,  const float* __restrict__ var,
    const float* __restrict__ dw,    const float* __restrict__ db,
    float* __restrict__ out)            // [B,H,W,2]
{
    __shared__ half8  hls[LH * LW];             // h tile + halo (9792 B)
    __shared__ half4  xls[LH * LW];             // x tile + halo (4896 B)
    __shared__ half2t cls[SLOTS * 4 * NG * 64]; // c state, 32 KB, lane-private

    const int tid  = threadIdx.x;
    const int lane = tid & 63, wave = tid >> 6;
    const int quad = lane >> 4, nlo = lane & 15;
    const bool lo8 = (nlo < 8);
    const int fc = nlo & 7;

    // B-fragments once for the whole run (L2-hot, 16 x 16B per lane)
    half8 bfh[10], bfl[6];
#pragma unroll
    for (int i = 0; i < 10; ++i)
        bfh[i] = *(const half8*)(blob + ((size_t)i * 64 + lane) * 8);
#pragma unroll
    for (int i = 0; i < 6; ++i)
        bfl[i] = *(const half8*)(blob + ((size_t)(10 + i) * 64 + lane) * 8);

    // bias, activation-scale folded (cols 16..23 are the g gate)
    const float bv0 = bias[nlo] * (-LOG2E);
    const float bv1 = bias[16 + nlo] * (lo8 ? 2.0f * LOG2E : -LOG2E);

    // fused-epilogue constants (used at t = TT-1)
    const float bn_s = gamma[fc] * rsqrtf(var[fc] + 1e-3f);
    const float bn_b = beta[fc] - mean[fc] * bn_s;
    const float dw0 = dw[fc * 2 + 0], dw1 = dw[fc * 2 + 1];
    const float db0 = db[0], db1 = db[1];

#pragma unroll 1
    for (int t = 0; t < TT; ++t) {
        const _Float16* hin  = (t & 1) ? h1 : h0;
        _Float16*       hout = (t & 1) ? h0 : h1;
        const bool first = (t == 0);
        const bool last  = (t == TT - 1);

#pragma unroll 1
        for (int sl = 0; sl < SLOTS; ++sl) {
            const int tile = (int)blockIdx.x + sl * NBLK;
            const int b  = tile >> 7;           // 128 tiles per batch image
            const int by = (tile >> 3) & 15;
            const int bx = tile & 7;

            // ============ PHASE A: issue ALL global loads to regs ============
            // x halo: 612 px, 3 slots/thread, 3 dwords each
            float xr[3][3];
            bool  xin[3];
#pragma unroll
            for (int k = 0; k < 3; ++k) {
                const int l = tid + k * 256;
                const bool in = (l < LH * LW);
                xin[k] = in;
                int r = l / LW, c = l - r * LW;
                int gy = by * THT + r - 1, gx = bx * TW + c - 1;
                const bool inb = in && (unsigned)gy < HH && (unsigned)gx < WW;
                const float* p = xg + (((size_t)(b * TT + t) * HH + gy) * WW + gx) * CIN;
                xr[k][0] = inb ? p[0] : 0.0f;
                xr[k][1] = inb ? p[1] : 0.0f;
                xr[k][2] = inb ? p[2] : 0.0f;
            }
            // h halo: 612 px, 3 slots/thread, 16B each
            half8 hr[3];
            if (!first) {
#pragma unroll
                for (int k = 0; k < 3; ++k) {
                    const int l = tid + k * 256;
                    const bool in = (l < LH * LW);
                    int r = l / LW, c = l - r * LW;
                    int gy = by * THT + r - 1, gx = bx * TW + c - 1;
                    const bool inb = in && (unsigned)gy < HH && (unsigned)gx < WW;
                    half8 v = {(_Float16)0, (_Float16)0, (_Float16)0, (_Float16)0,
                               (_Float16)0, (_Float16)0, (_Float16)0, (_Float16)0};
                    if (inb) v = *(const half8*)(hin + ((size_t)(b * HH + gy) * WW + gx) * FF);
                    hr[k] = v;
                }
            }

            // barrier: previous slot's LDS reads must be done before overwrite
            __syncthreads();

            // ============ PHASE B: LDS writes ============
#pragma unroll
            for (int k = 0; k < 3; ++k) {
                if (xin[k]) {
                    half4 vh;
                    vh.x = (_Float16)xr[k][0];
                    vh.y = (_Float16)xr[k][1];
                    vh.z = (_Float16)xr[k][2];
                    vh.w = (_Float16)0;
                    xls[tid + k * 256] = vh;
                }
            }
            if (!first) {
#pragma unroll
                for (int k = 0; k < 3; ++k)
                    if (xin[k]) hls[tid + k * 256] = hr[k];
            }
            __syncthreads();

#pragma unroll
            for (int g = 0; g < NG; ++g) {
                const int lr  = wave * 4 + (g >> 1);   // local row of this strip
                const int gx0 = (g & 1) * 16;          // strip start col
                const int lc  = gx0 + nlo;             // A-op: m = lane&15 -> pixel col

                // ---- x A fragments from LDS ----
                const int t0 = 2 * quad, t1 = t0 + 1;
                half4 p  = xls[(lr + t0 / 3) * LW + lc + t0 % 3];
                half4 q  = xls[(lr + t1 / 3) * LW + lc + t1 % 3];
                half4 s8 = xls[(lr + 2) * LW + lc + 2];            // tap 8
                half8 a_xA = (half8){p.x, p.y, p.z, p.w, q.x, q.y, q.z, q.w};
                half8 a_xB = (half8){s8.x, s8.y, s8.z, s8.w, s8.x, s8.y, s8.z, s8.w};

                floatx4 acc0 = {bv0, bv0, bv0, bv0};
                floatx4 acc1 = {bv1, bv1, bv1, bv1};
                acc0 = MFMA(a_xA, bfh[0], acc0);  acc1 = MFMA(a_xA, bfh[1], acc1);
                acc0 = MFMA(a_xB, bfh[2], acc0);  acc1 = MFMA(a_xB, bfh[3], acc1);
                if (!first) {
#pragma unroll
                    for (int c = 0; c < 3; ++c) {
                        int tap = c * 4 + quad;
                        if (tap > 8) tap = 8;          // padded taps: B rows zero
                        half8 ah = hls[(lr + tap / 3) * LW + lc + tap % 3];
                        acc0 = MFMA(ah, bfh[4 + c * 2], acc0);
                        acc1 = MFMA(ah, bfh[5 + c * 2], acc1);
                        acc0 = MFMA(ah, bfl[c * 2 + 0], acc0);
                        acc1 = MFMA(ah, bfl[c * 2 + 1], acc1);
                    }
                }

                // ---- gate phase ----
                // C layout: pixel m = quad*4+reg, ch = nlo (acc0) / nlo+16 (acc1).
                // Lanes ch<8 hold (i,g), ch+8 hold (f,o): exchange via shfl_xor(8).
                float s0 = lo8 ? acc0[2] : acc0[0]; float r0 = __shfl_xor(s0, 8, 64);
                float s1 = lo8 ? acc0[3] : acc0[1]; float r1 = __shfl_xor(s1, 8, 64);
                float s2 = lo8 ? acc1[2] : acc1[0]; float r2 = __shfl_xor(s2, 8, 64);
                float s3 = lo8 ? acc1[3] : acc1[1]; float r3 = __shfl_xor(s3, 8, 64);

                const float zi0 = lo8 ? acc0[0] : r0, zi1 = lo8 ? acc0[1] : r1;
                const float zf0 = lo8 ? r0 : acc0[2], zf1 = lo8 ? r1 : acc0[3];
                const float zg0 = lo8 ? acc1[0] : r2, zg1 = lo8 ? acc1[1] : r3;
                const float zo0 = lo8 ? r2 : acc1[2], zo1 = lo8 ? r3 : acc1[3];

                const int cidx = ((sl * 4 + wave) * NG + g) * 64 + lane;
                float c0 = 0.f, c1 = 0.f;
                if (!first) {
                    half2t cp = cls[cidx];
                    c0 = (float)cp.x; c1 = (float)cp.y;
                }

                const float ii0 = sig2(zi0), ff0 = sig2(zf0), gg0 = tanh2(zg0), oo0 = sig2(zo0);
                const float cn0 = ff0 * c0 + ii0 * gg0;
                const float hn0 = oo0 * tanh2(cn0 * (2.0f * LOG2E));
                const float ii1 = sig2(zi1), ff1 = sig2(zf1), gg1 = tanh2(zg1), oo1 = sig2(zo1);
                const float cn1 = ff1 * c1 + ii1 * gg1;
                const float hn1 = oo1 * tanh2(cn1 * (2.0f * LOG2E));

                const int m0 = quad * 4 + (lo8 ? 0 : 2);
                const int gy = by * THT + lr;
                if (!last) {
                    // c writeback to LDS (lane-private, conflict-free)
                    half2t cc; cc.x = (_Float16)cn0; cc.y = (_Float16)cn1;
                    cls[cidx] = cc;
                    // h writeback: lane owns channel fc for pixels m0, m0+1
                    _Float16* hp = hout + ((size_t)(b * HH + gy) * WW + bx * TW + gx0 + m0) * FF + fc;
                    hp[0]  = (_Float16)hn0;
                    hp[FF] = (_Float16)hn1;
                } else {
                    // ---- fused epilogue: BN -> LeakyReLU(0.3) -> Dense(8->2) ----
                    float y0 = bn_s * hn0 + bn_b; y0 = (y0 >= 0.f) ? y0 : 0.3f * y0;
                    float y1 = bn_s * hn1 + bn_b; y1 = (y1 >= 0.f) ? y1 : 0.3f * y1;
                    float p00 = y0 * dw0, p01 = y0 * dw1;
                    float p10 = y1 * dw0, p11 = y1 * dw1;
#pragma unroll
                    for (int m = 1; m <= 4; m <<= 1) {
                        p00 += __shfl_xor(p00, m, 64);
                        p01 += __shfl_xor(p01, m, 64);
                        p10 += __shfl_xor(p10, m, 64);
                        p11 += __shfl_xor(p11, m, 64);
                    }
                    const int j = nlo & 7;
                    if (j < 4) {
                        const int px = m0 + (j >> 1);
                        const int k  = j & 1;
                        float val = (j == 0 ? p00 : j == 1 ? p01 : j == 2 ? p10 : p11)
                                    + (k ? db1 : db0);
                        out[((size_t)(b * HH + gy) * WW + bx * TW + gx0 + px) * 2 + k] = val;
                    }
                }
            }
        }
        if (t < TT - 1) grid_barrier(bar);
    }
}

extern "C" void kernel_launch(void* const* d_in, const int* in_sizes, int n_in,
                              void* d_out, int out_size, void* d_ws, size_t ws_size,
                              hipStream_t stream) {
    const float* x     = (const float*)d_in[0];
    const float* wk    = (const float*)d_in[1];
    const float* wr    = (const float*)d_in[2];
    const float* bias  = (const float*)d_in[3];
    const float* gamma = (const float*)d_in[4];
    const float* beta  = (const float*)d_in[5];
    const float* mean  = (const float*)d_in[6];
    const float* var   = (const float*)d_in[7];
    const float* dw    = (const float*)d_in[8];
    const float* db    = (const float*)d_in[9];
    float* out = (float*)d_out;

    // ws: blob 32KB | bar 256B | h0 fp16 16.78MB | h1 fp16 16.78MB
    const size_t state = (size_t)BB * HH * WW * FF;
    _Float16* blob = (_Float16*)d_ws;
    unsigned* bar  = (unsigned*)((char*)d_ws + 32768);
    _Float16* h0   = (_Float16*)((char*)d_ws + 32768 + 256);
    _Float16* h1   = h0 + state;

    build_frags<<<1, 64, 0, stream>>>(wk, wr, blob, bar);

    lstm_all<<<dim3(NBLK), dim3(256), 0, stream>>>(
        x, blob, bias, h0, h1, bar,
        gamma, beta, mean, var, dw, db, out);
}